// Round 2
// baseline (98.542 us; speedup 1.0000x reference)
//
#include <hip/hip_runtime.h>

// CrAKNVectorAttention: the reference computes
//   w = softmax(h, axis=-2); out[i,k] = sum_j w[i,j,k] * v[i,k]
// softmax over j sums to 1 exactly, so out == v == feat @ Wv + bv
// (up to f32 rounding ~1e-6 relative). The whole module collapses to a
// single N x C x C bias-GEMM.
//
// Dtypes: all float32 (round-1 NaN proved inputs are NOT bf16 — reading
// f32 buffers as bf16 injected NaN bit patterns).
// Inputs: d_in[0]=feat [N,C], d_in[9]=Wv [C,C], d_in[10]=bv [C].
// Output: f32 [N,C].

#define NN 1024
#define CC 256
#define TM 4  // rows per block: 256 blocks -> ~1 per CU

__global__ __launch_bounds__(256) void v_bias_gemm(
    const float* __restrict__ feat,
    const float* __restrict__ Wv,
    const float* __restrict__ bv,
    float* __restrict__ out)
{
    __shared__ float sf[TM][CC];
    const int c = threadIdx.x;            // output column, 0..255
    const int row0 = blockIdx.x * TM;

    // Stage TM feat rows into LDS (coalesced f32 loads).
    #pragma unroll
    for (int r = 0; r < TM; ++r) {
        sf[r][c] = feat[(row0 + r) * CC + c];
    }
    __syncthreads();

    float acc[TM];
    const float b = bv[c];
    #pragma unroll
    for (int r = 0; r < TM; ++r) acc[r] = b;

    // K-loop: thread c reads Wv[k][c] (coalesced across the wave);
    // sf[r][k] is a wave-uniform LDS broadcast (conflict-free).
    #pragma unroll 4
    for (int k = 0; k < CC; ++k) {
        const float w = Wv[k * CC + c];
        #pragma unroll
        for (int r = 0; r < TM; ++r)
            acc[r] = fmaf(sf[r][k], w, acc[r]);
    }

    #pragma unroll
    for (int r = 0; r < TM; ++r)
        out[(row0 + r) * CC + c] = acc[r];
}

extern "C" void kernel_launch(void* const* d_in, const int* in_sizes, int n_in,
                              void* d_out, int out_size, void* d_ws, size_t ws_size,
                              hipStream_t stream) {
    (void)in_sizes; (void)n_in; (void)d_ws; (void)ws_size; (void)out_size;
    const float* feat = (const float*)d_in[0];
    const float* Wv   = (const float*)d_in[9];
    const float* bv   = (const float*)d_in[10];
    float* out = (float*)d_out;

    dim3 grid(NN / TM);   // 256 blocks
    dim3 block(CC);       // 256 threads
    v_bias_gemm<<<grid, block, 0, stream>>>(feat, Wv, bv, out);
}

// Round 3
// 93.819 us; speedup vs baseline: 1.0503x; 1.0503x over previous
//
#include <hip/hip_runtime.h>

// CrAKNVectorAttention: softmax over j sums to 1, so
//   out[i,k] = v[i,k] * sum_j softmax_j(h)[i,j,k] = v[i,k] = (feat @ Wv + bv)[i,k].
// The whole module collapses to one N x C x C f32 bias-GEMM.
//
// R2 post-mortem: passed (absmax 3.9e-3), dur_us 98.5 dominated by harness
// ws-poison fills (268 MB @ 84% HBM peak, top-5 dispatches). Kernel itself was
// LDS-issue bound (16 ds_read_b32 broadcasts per k per CU). This version drops
// LDS: feat reads are block-uniform -> compiler scalarizes to s_load (constant
// cache), leaving 4 v_fmac (SGPR operand) + 1 coalesced Wv load per k.
//
// Inputs (f32): d_in[0]=feat [N,C], d_in[9]=Wv [C,C], d_in[10]=bv [C].
// Output: f32 [N,C].

#define NN 1024
#define CC 256
#define TM 4  // rows per block: 256 blocks -> 1/CU; Wv L2 traffic 64 MB (~1.9 us floor)

__global__ __launch_bounds__(256) void v_bias_gemm(
    const float* __restrict__ feat,
    const float* __restrict__ Wv,
    const float* __restrict__ bv,
    float* __restrict__ out)
{
    const int c = threadIdx.x;             // output column, 0..255
    const int row0 = blockIdx.x * TM;
    const float* __restrict__ f0 = feat + row0 * CC;  // block-uniform base

    // acc init with bias
    const float b = bv[c];
    float acc0 = b, acc1 = b, acc2 = b, acc3 = b;

    // K-loop: Wv[k][c] coalesced vector load (256 B/wave);
    // f0[r*CC+k] is block-uniform -> s_load through constant cache.
    #pragma unroll 8
    for (int k = 0; k < CC; ++k) {
        const float w = Wv[k * CC + c];
        acc0 = fmaf(f0[0 * CC + k], w, acc0);
        acc1 = fmaf(f0[1 * CC + k], w, acc1);
        acc2 = fmaf(f0[2 * CC + k], w, acc2);
        acc3 = fmaf(f0[3 * CC + k], w, acc3);
    }

    out[(row0 + 0) * CC + c] = acc0;
    out[(row0 + 1) * CC + c] = acc1;
    out[(row0 + 2) * CC + c] = acc2;
    out[(row0 + 3) * CC + c] = acc3;
}

extern "C" void kernel_launch(void* const* d_in, const int* in_sizes, int n_in,
                              void* d_out, int out_size, void* d_ws, size_t ws_size,
                              hipStream_t stream) {
    (void)in_sizes; (void)n_in; (void)d_ws; (void)ws_size; (void)out_size;
    const float* feat = (const float*)d_in[0];
    const float* Wv   = (const float*)d_in[9];
    const float* bv   = (const float*)d_in[10];
    float* out = (float*)d_out;

    dim3 grid(NN / TM);   // 256 blocks
    dim3 block(CC);       // 256 threads
    v_bias_gemm<<<grid, block, 0, stream>>>(feat, Wv, bv, out);
}